// Round 9
// baseline (4083.600 us; speedup 1.0000x reference)
//
#include <hip/hip_runtime.h>

// ---------------- workspace layout (floats) ----------------
constexpr size_t OFF_XN  = 0;                      // 512*1024
constexpr size_t OFF_PF  = 524288;                 // 32768*128
constexpr size_t OFF_W2A = OFF_PF  + 4194304;      // [(cc*3+k)*128+d]
constexpr size_t OFF_W1B = OFF_W2A + 49152;
constexpr size_t OFF_W2B = OFF_W1B + 49152;
constexpr size_t OFF_PW  = OFF_W2B + 49152;        // [(c*16+k)*128+d]
constexpr size_t OFF_UPW = OFF_PW  + 262144;       // [(j*128+e)*128+d]
constexpr size_t OFF_W1D = OFF_UPW + 262144;       // [(c*3+k)*64+o]
constexpr size_t OFF_EMT = OFF_W1D + 24576;        // [j*128+d]
constexpr size_t OFF_EN  = OFF_EMT + 131072;       // 1024
constexpr size_t OFF_RP  = OFF_EN  + 1024;         // 8192
constexpr size_t OFF_VP  = OFF_RP  + 8192;         // 4096
constexpr size_t OFF_IND = OFF_VP  + 4096;         // 32768 int
// total ~21.7 MB

#define DI __device__ __forceinline__

// ---------------- prep: weight transposes + embedT + |e|^2 ----------------
__global__ __launch_bounds__(256) void k_prep(
    const float* __restrict__ w2a, const float* __restrict__ w1b, const float* __restrict__ w2b,
    const float* __restrict__ pw,  const float* __restrict__ upw, const float* __restrict__ w1d,
    const float* __restrict__ em,  float* __restrict__ ws)
{
  int tid = blockIdx.x * 256 + threadIdx.x;
  int stride = gridDim.x * 256;
  for (int i = tid; i < 128*128*3; i += stride) {
    int d = i / 384, r = i % 384;          // r = cc*3+k
    ws[OFF_W2A + (size_t)r*128 + d] = w2a[i];
    ws[OFF_W1B + (size_t)r*128 + d] = w1b[i];
    ws[OFF_W2B + (size_t)r*128 + d] = w2b[i];
  }
  for (int i = tid; i < 128*128*16; i += stride) {
    int d = i / 2048, r = i % 2048;        // r = c*16+k
    ws[OFF_PW + (size_t)r*128 + d] = pw[i];
  }
  for (int i = tid; i < 128*128*16; i += stride) {
    int e = i / 2048, rem = i % 2048;
    int d = rem / 16, j = rem % 16;
    ws[OFF_UPW + (size_t)(j*128 + e)*128 + d] = upw[i];
  }
  for (int i = tid; i < 64*128*3; i += stride) {
    int o = i / 384, r = i % 384;          // r = c*3+k
    ws[OFF_W1D + (size_t)r*64 + o] = w1d[i];
  }
  for (int j = tid; j < 1024; j += stride) {
    float s = 0.f;
    for (int d = 0; d < 128; ++d) {
      float v = em[d*1024 + j];
      ws[OFF_EMT + (size_t)j*128 + d] = v;
      s = fmaf(v, v, s);
    }
    ws[OFF_EN + j] = s;
  }
}

// ---------------- RevIN ----------------
__global__ __launch_bounds__(256) void k_revin(
    const float* __restrict__ x, const float* __restrict__ rw, const float* __restrict__ rb,
    float* __restrict__ xn)
{
  int n = blockIdx.x;            // sample = b*8 + c
  int b = n >> 3, c = n & 7;
  int t = threadIdx.x;
  const float* xp = x + (size_t)b*8192 + c;
  float v[4]; float s = 0.f, s2 = 0.f;
  #pragma unroll
  for (int i = 0; i < 4; ++i) {
    v[i] = xp[(size_t)(t + i*256)*8];
    s += v[i]; s2 = fmaf(v[i], v[i], s2);
  }
  __shared__ float sh[8];
  __shared__ float st[2];
  for (int o = 32; o; o >>= 1) { s += __shfl_down(s, o, 64); s2 += __shfl_down(s2, o, 64); }
  if ((t & 63) == 0) { sh[t >> 6] = s; sh[4 + (t >> 6)] = s2; }
  __syncthreads();
  if (t == 0) {
    float S = sh[0]+sh[1]+sh[2]+sh[3];
    float S2 = sh[4]+sh[5]+sh[6]+sh[7];
    float mu = S * (1.f/1024.f);
    float var = S2 * (1.f/1024.f) - mu*mu;
    st[0] = mu;
    st[1] = 1.f / sqrtf(var + 1e-5f);
  }
  __syncthreads();
  float mu = st[0], inv = st[1], w0 = rw[0], b0 = rb[0];
  #pragma unroll
  for (int i = 0; i < 4; ++i)
    xn[(size_t)n*1024 + t + i*256] = fmaf((v[i]-mu)*inv, w0, b0);
}

// ---------------- fully fused encoder ----------------
// block = (n, tile of 64 cols). 512 thr, 8 waves; wave w owns d-slice 16; lane = col.
// bufA [64][70]: h1a half (cc-split); later patchify partials [8cq][4p][128dd].
// bufB [128][68]: out0 (cols l0-4..l0+63) -> h1b (cols l0-2..l0+63) -> out1 (cols l0..l0+63).
constexpr int STA = 70;
constexpr int STB = 68;

__global__ __launch_bounds__(512) void k_enc(
    const float* __restrict__ xn, float* __restrict__ pf,
    const float* __restrict__ w1a, const float* __restrict__ b1a,
    const float* __restrict__ w2aT, const float* __restrict__ b2a,
    const float* __restrict__ wd,  const float* __restrict__ bd,
    const float* __restrict__ w1bT, const float* __restrict__ b1b,
    const float* __restrict__ w2bT, const float* __restrict__ b2b,
    const float* __restrict__ pwT, const float* __restrict__ pb)
{
  __shared__ float xs[72];
  __shared__ __align__(16) float bufA[64*STA];
  __shared__ __align__(16) float bufB[128*STB];
  int n = blockIdx.x >> 4, tile = blockIdx.x & 15;
  int l0 = tile * 64;
  int t = threadIdx.x;
  int lane = t & 63;
  int w = __builtin_amdgcn_readfirstlane(t >> 6);
  int d0 = w * 16;

  if (t < 72) {
    int gl = l0 - 8 + t;
    xs[t] = (gl >= 0) ? xn[(size_t)n*1024 + gl] : 0.f;
  }
  __syncthreads();

  float acc2[16];
  #pragma unroll
  for (int i = 0; i < 16; ++i) acc2[i] = 0.f;
  float hacc[4] = {0.f, 0.f, 0.f, 0.f};

  // ---- h1a (cc halves) + conv2 accumulation (verified R7 maps) ----
  for (int rep = 0; rep < 2; ++rep) {
    {                                   // h1a rows rep*64..+63, cols j<70 <-> l = l0-6+j
      int row = t & 63, colg = t >> 6;
      int c = rep*64 + row;
      float w0 = w1a[c*3+0], w1 = w1a[c*3+1], w2 = w1a[c*3+2], bb = b1a[c];
      #pragma unroll
      for (int i = 0; i < 9; ++i) {
        int j = colg*9 + i;
        if (j < 70) {
          float v = fmaf(w0, xs[j], fmaf(w1, xs[j+1], fmaf(w2, xs[j+2], bb)));
          bufA[row*STA + j] = (l0 - 6 + j >= 0) ? fmaxf(v, 0.f) : 0.f;
        }
      }
    }
    __syncthreads();
    for (int cc2 = 0; cc2 < 64; ++cc2) {   // conv2 main: out0 col l = l0+lane
      float r0 = bufA[cc2*STA + lane + 4];
      float r1 = bufA[cc2*STA + lane + 5];
      float r2 = bufA[cc2*STA + lane + 6];
      const float4* wp = (const float4*)(w2aT + (size_t)(rep*64 + cc2)*384 + d0);
      #pragma unroll
      for (int jj = 0; jj < 4; ++jj) {
        float4 a = wp[jj], b = wp[32+jj], c4 = wp[64+jj];
        acc2[jj*4+0] = fmaf(a.x, r0, fmaf(b.x, r1, fmaf(c4.x, r2, acc2[jj*4+0])));
        acc2[jj*4+1] = fmaf(a.y, r0, fmaf(b.y, r1, fmaf(c4.y, r2, acc2[jj*4+1])));
        acc2[jj*4+2] = fmaf(a.z, r0, fmaf(b.z, r1, fmaf(c4.z, r2, acc2[jj*4+2])));
        acc2[jj*4+3] = fmaf(a.w, r0, fmaf(b.w, r1, fmaf(c4.w, r2, acc2[jj*4+3])));
      }
    }
    if (t < 128) {                         // conv2 halo: out0 cols l0-4..l0-1, d = t
      for (int cc2 = 0; cc2 < 64; ++cc2) {
        const float* wp = w2aT + (size_t)(rep*64 + cc2)*384 + t;
        float w0 = wp[0], w1 = wp[128], w2 = wp[256];
        float q0 = bufA[cc2*STA+0], q1 = bufA[cc2*STA+1], q2 = bufA[cc2*STA+2],
              q3 = bufA[cc2*STA+3], q4 = bufA[cc2*STA+4], q5 = bufA[cc2*STA+5];
        hacc[0] = fmaf(w0, q0, fmaf(w1, q1, fmaf(w2, q2, hacc[0])));
        hacc[1] = fmaf(w0, q1, fmaf(w1, q2, fmaf(w2, q3, hacc[1])));
        hacc[2] = fmaf(w0, q2, fmaf(w1, q3, fmaf(w2, q4, hacc[2])));
        hacc[3] = fmaf(w0, q3, fmaf(w1, q4, fmaf(w2, q5, hacc[3])));
      }
    }
    __syncthreads();
  }

  // ---- out0 epilogue -> bufB (col j <-> l = l0-4+j); keep residual in regs ----
  float res[16];
  {
    float xv = xs[lane + 8];
    #pragma unroll
    for (int i = 0; i < 16; ++i) {
      int d = d0 + i;
      float o = fmaxf(fmaxf(acc2[i] + b2a[d], 0.f) + fmaf(wd[d], xv, bd[d]), 0.f);
      res[i] = o;                       // out0[d][l0+lane] kept for out1 residual
      bufB[d*STB + lane + 4] = o;
    }
    if (t < 128) {
      #pragma unroll
      for (int h = 0; h < 4; ++h) {
        int l = l0 - 4 + h;
        float o = 0.f;
        if (l >= 0)
          o = fmaxf(fmaxf(hacc[h] + b2a[t], 0.f) + fmaf(wd[t], xs[h+4], bd[t]), 0.f);
        bufB[t*STB + h] = o;
      }
    }
  }
  __syncthreads();

  // ---- conv3 single pass: h1b in regs (wave owns d-slice 16), then overwrite bufB ----
  {
    float acc3[16];
    #pragma unroll
    for (int i = 0; i < 16; ++i) acc3[i] = 0.f;
    // main: h1b[d0+i][gcol = l0-2+lane]; reads out0 window jb = lane..lane+2
    for (int cc = 0; cc < 128; ++cc) {
      float r0 = bufB[cc*STB + lane];
      float r1 = bufB[cc*STB + lane + 1];
      float r2 = bufB[cc*STB + lane + 2];
      const float4* wp = (const float4*)(w1bT + (size_t)cc*384 + d0);
      #pragma unroll
      for (int jj = 0; jj < 4; ++jj) {
        float4 a = wp[jj], b = wp[32+jj], c4 = wp[64+jj];
        acc3[jj*4+0] = fmaf(a.x, r0, fmaf(b.x, r1, fmaf(c4.x, r2, acc3[jj*4+0])));
        acc3[jj*4+1] = fmaf(a.y, r0, fmaf(b.y, r1, fmaf(c4.y, r2, acc3[jj*4+1])));
        acc3[jj*4+2] = fmaf(a.z, r0, fmaf(b.z, r1, fmaf(c4.z, r2, acc3[jj*4+2])));
        acc3[jj*4+3] = fmaf(a.w, r0, fmaf(b.w, r1, fmaf(c4.w, r2, acc3[jj*4+3])));
      }
    }
    // halo: h1b cols jh = 64,65 (gcol = l0+62, l0+63); out0 window jb = jh..jh+2
    float haccb = 0.f;
    int hrow = t & 127, hc = 64 + (t >> 7);   // t<256 active
    if (t < 256) {
      for (int cc = 0; cc < 128; ++cc) {
        float q0 = bufB[cc*STB + hc];
        float q1 = bufB[cc*STB + hc + 1];
        float q2 = bufB[cc*STB + hc + 2];
        const float* wp = w1bT + (size_t)cc*384 + hrow;
        haccb = fmaf(wp[0], q0, fmaf(wp[128], q1, fmaf(wp[256], q2, haccb)));
      }
    }
    __syncthreads();   // all out0 reads done; bufB reusable
    {
      bool valid = (l0 - 2 + lane >= 0);
      #pragma unroll
      for (int i = 0; i < 16; ++i)
        bufB[(d0+i)*STB + lane] = valid ? fmaxf(acc3[i] + b1b[d0+i], 0.f) : 0.f;
      if (t < 256)
        bufB[hrow*STB + hc] = fmaxf(haccb + b1b[hrow], 0.f);
    }
  }
  __syncthreads();

  // ---- conv4 single pass: out1 col l = l0+lane; h1b window = bufB[row][lane..lane+2] ----
  float acc4[16];
  #pragma unroll
  for (int i = 0; i < 16; ++i) acc4[i] = 0.f;
  for (int row = 0; row < 128; ++row) {
    float r0 = bufB[row*STB + lane];
    float r1 = bufB[row*STB + lane + 1];
    float r2 = bufB[row*STB + lane + 2];
    const float4* wp = (const float4*)(w2bT + (size_t)row*384 + d0);
    #pragma unroll
    for (int jj = 0; jj < 4; ++jj) {
      float4 a = wp[jj], b = wp[32+jj], c4 = wp[64+jj];
      acc4[jj*4+0] = fmaf(a.x, r0, fmaf(b.x, r1, fmaf(c4.x, r2, acc4[jj*4+0])));
      acc4[jj*4+1] = fmaf(a.y, r0, fmaf(b.y, r1, fmaf(c4.y, r2, acc4[jj*4+1])));
      acc4[jj*4+2] = fmaf(a.z, r0, fmaf(b.z, r1, fmaf(c4.z, r2, acc4[jj*4+2])));
      acc4[jj*4+3] = fmaf(a.w, r0, fmaf(b.w, r1, fmaf(c4.w, r2, acc4[jj*4+3])));
    }
  }
  __syncthreads();   // all h1b reads done
  // ---- out1 epilogue (residual from regs) -> bufB cols 0..63 ----
  #pragma unroll
  for (int i = 0; i < 16; ++i)
    bufB[(d0+i)*STB + lane] = fmaxf(fmaxf(acc4[i] + b2b[d0+i], 0.f) + res[i], 0.f);
  __syncthreads();

  // ---- patchify: thread (cq = t>>6, ddp = t&63) -> dd = 2ddp, 2ddp+1; c in [16cq,16cq+16) ----
  {
    int cq = t >> 6, ddp = t & 63;
    float acc[4][2] = {};
    for (int cl = 0; cl < 16; ++cl) {
      int c = cq*16 + cl;
      const float* row = bufB + c*STB;
      const float* wbase = pwT + (size_t)c*2048 + 2*ddp;
      #pragma unroll
      for (int k4 = 0; k4 < 4; ++k4) {
        float2 wv0 = *(const float2*)(wbase + (size_t)(k4*4+0)*128);
        float2 wv1 = *(const float2*)(wbase + (size_t)(k4*4+1)*128);
        float2 wv2 = *(const float2*)(wbase + (size_t)(k4*4+2)*128);
        float2 wv3 = *(const float2*)(wbase + (size_t)(k4*4+3)*128);
        #pragma unroll
        for (int p = 0; p < 4; ++p) {
          float4 av = *(const float4*)(row + p*16 + k4*4);
          acc[p][0] = fmaf(av.x, wv0.x, acc[p][0]);
          acc[p][1] = fmaf(av.x, wv0.y, acc[p][1]);
          acc[p][0] = fmaf(av.y, wv1.x, acc[p][0]);
          acc[p][1] = fmaf(av.y, wv1.y, acc[p][1]);
          acc[p][0] = fmaf(av.z, wv2.x, acc[p][0]);
          acc[p][1] = fmaf(av.z, wv2.y, acc[p][1]);
          acc[p][0] = fmaf(av.w, wv3.x, acc[p][0]);
          acc[p][1] = fmaf(av.w, wv3.y, acc[p][1]);
        }
      }
    }
    #pragma unroll
    for (int p = 0; p < 4; ++p)
      *(float2*)(bufA + (cq*4 + p)*128 + 2*ddp) = make_float2(acc[p][0], acc[p][1]);
  }
  __syncthreads();
  {
    int p = t >> 7, dd = t & 127;
    float s = 0.f;
    #pragma unroll
    for (int cq = 0; cq < 8; ++cq) s += bufA[(cq*4 + p)*128 + dd];
    pf[((size_t)n*64 + tile*4 + p)*128 + dd] = s + pb[dd];
  }
}

// ---------------- VQ argmin: dist' = |e|^2 - 2 f.e ----------------
__global__ __launch_bounds__(256) void k_vq(float* ws)
{
  __shared__ __align__(16) float fT[128*132];
  __shared__ __align__(16) float ech[64*128];
  __shared__ float ens[64];
  __shared__ float2 red[128*16];
  const float* pf  = ws + OFF_PF;
  const float* emT = ws + OFF_EMT;
  const float* en  = ws + OFF_EN;
  int* ind = (int*)(ws + OFF_IND);

  int t = threadIdx.x;
  int r0 = blockIdx.x * 128;
  for (int s = t; s < 16384; s += 256) {
    int rr = s >> 7, d = s & 127;
    fT[d*132 + rr] = pf[(size_t)(r0 + rr)*128 + d];
  }
  int rg = t & 15, jg = t >> 4;
  float bv[8]; int bi[8];
  #pragma unroll
  for (int r = 0; r < 8; ++r) { bv[r] = 3.4e38f; bi[r] = 0; }

  for (int ch = 0; ch < 16; ++ch) {
    __syncthreads();
    {
      const float4* src = (const float4*)(emT + (size_t)ch*8192);
      for (int q = t; q < 2048; q += 256) {
        int jj = q >> 5, dq4 = q & 31;
        *(float4*)(ech + jj*128 + ((dq4*4) ^ ((jj&7)<<2))) = src[q];
      }
      if (t < 64) ens[t] = en[ch*64 + t];
    }
    __syncthreads();
    float acc[8][4] = {};
    for (int db = 0; db < 128; db += 4) {
      float4 e0 = *(const float4*)(ech + (jg*4+0)*128 + (db ^ (((jg*4+0)&7)<<2)));
      float4 e1 = *(const float4*)(ech + (jg*4+1)*128 + (db ^ (((jg*4+1)&7)<<2)));
      float4 e2 = *(const float4*)(ech + (jg*4+2)*128 + (db ^ (((jg*4+2)&7)<<2)));
      float4 e3 = *(const float4*)(ech + (jg*4+3)*128 + (db ^ (((jg*4+3)&7)<<2)));
      #pragma unroll
      for (int u = 0; u < 4; ++u) {
        const float* fp = fT + (db+u)*132 + rg*8;
        float4 fa = *(const float4*)fp;
        float4 fb = *(const float4*)(fp + 4);
        float fv[8] = {fa.x,fa.y,fa.z,fa.w,fb.x,fb.y,fb.z,fb.w};
        float ev[4] = { ((const float*)&e0)[u], ((const float*)&e1)[u],
                        ((const float*)&e2)[u], ((const float*)&e3)[u] };
        #pragma unroll
        for (int r = 0; r < 8; ++r)
          #pragma unroll
          for (int j = 0; j < 4; ++j)
            acc[r][j] = fmaf(fv[r], ev[j], acc[r][j]);
      }
    }
    #pragma unroll
    for (int r = 0; r < 8; ++r)
      #pragma unroll
      for (int j = 0; j < 4; ++j) {
        float dist = ens[jg*4 + j] - 2.f*acc[r][j];
        int code = ch*64 + jg*4 + j;
        if (dist < bv[r]) { bv[r] = dist; bi[r] = code; }
      }
  }
  __syncthreads();
  #pragma unroll
  for (int r = 0; r < 8; ++r)
    red[(rg*8 + r)*16 + jg] = make_float2(bv[r], __int_as_float(bi[r]));
  __syncthreads();
  if (t < 128) {
    float2 v0 = red[t*16 + 0];
    float best = v0.x; int besti = __float_as_int(v0.y);
    for (int j = 1; j < 16; ++j) {
      float2 v = red[t*16 + j];
      int vi = __float_as_int(v.y);
      if (v.x < best || (v.x == best && vi < besti)) { best = v.x; besti = vi; }
    }
    ind[r0 + t] = besti;
  }
}

// ---------------- gather: z_q -> d_out, vq-loss partials ----------------
__global__ __launch_bounds__(256) void k_gather(float* ws, float* __restrict__ dout)
{
  const float* pf  = ws + OFF_PF;
  const float* emT = ws + OFF_EMT;
  const int* ind = (const int*)(ws + OFF_IND);
  float* vq_part = ws + OFF_VP;

  int t = threadIdx.x;
  int d = t & 127;
  float s = 0.f;
  #pragma unroll
  for (int it = 0; it < 4; ++it) {
    int rr = (t >> 7) + it*2;
    size_t row = (size_t)blockIdx.x*8 + rr;
    int idx = ind[row];
    float q = emT[(size_t)idx*128 + d];
    float f = pf[row*128 + d];
    float qm = q - f;
    dout[row*128 + d] = f + qm;
    s = fmaf(qm, qm, s);
  }
  __shared__ float sh[4];
  for (int o = 32; o; o >>= 1) s += __shfl_down(s, o, 64);
  if ((t & 63) == 0) sh[t >> 6] = s;
  __syncthreads();
  if (t == 0) vq_part[blockIdx.x] = sh[0]+sh[1]+sh[2]+sh[3];
}

DI float gelu_f(float x) {
  float u = x * fmaf(0.0356774081f, x*x, 0.7978845608f);
  float e = __expf(2.f * u);
  float th = 1.f - 2.f / (e + 1.f);
  return 0.5f * x * (1.f + th);
}

// ---------------- decoder: tile=64, 512 threads; D1 = encoder-style conv ----------------
__global__ __launch_bounds__(512) void k_decoder(
    const float* __restrict__ zq, float* ws,
    const float* __restrict__ upb, const float* __restrict__ db1,
    const float* __restrict__ dw2, const float* __restrict__ db2)
{
  constexpr int UPS = 70;   // up col j <-> l = l0-2+j, j=0..67 used
  constexpr int DS  = 70;   // d1 col j <-> l = l0-1+j, j=0..65 used
  __shared__ __align__(16) float ztT[128*8];
  __shared__ __align__(16) float up_s[128*UPS];
  __shared__ __align__(16) float dsh[64*DS];
  __shared__ __align__(16) float wd2[200];

  const float* upwT = ws + OFF_UPW;
  const float* w1dT = ws + OFF_W1D;
  const float* xn   = ws + OFF_XN;
  float* recon_part = ws + OFF_RP;

  int blk = blockIdx.x;
  int n = blk >> 4, tile = blk & 15;
  int l0 = tile*64, p0 = tile*4;
  int t = threadIdx.x;
  int lane = t & 63;
  int w = __builtin_amdgcn_readfirstlane(t >> 6);

  for (int s = t; s < 768; s += 512) {
    int e = s & 127, pi = s >> 7;
    int p = p0 - 1 + pi;
    ztT[e*8 + pi] = (p >= 0 && p < 64) ? zq[((size_t)n*64 + p)*128 + e] : 0.f;
  }
  __syncthreads();

  {
    int jj = t >> 5;
    int d4 = (t & 31) * 4;
    float acc[6][4] = {};
    const float* wbase = upwT + (size_t)jj*16384 + d4;
    for (int e = 0; e < 128; ++e) {
      float4 z0 = *(const float4*)(ztT + e*8);
      float2 z1 = *(const float2*)(ztT + e*8 + 4);
      float zr[6] = {z0.x, z0.y, z0.z, z0.w, z1.x, z1.y};
      float4 wv = *(const float4*)(wbase + (size_t)e*128);
      #pragma unroll
      for (int pi = 0; pi < 6; ++pi) {
        acc[pi][0] = fmaf(zr[pi], wv.x, acc[pi][0]);
        acc[pi][1] = fmaf(zr[pi], wv.y, acc[pi][1]);
        acc[pi][2] = fmaf(zr[pi], wv.z, acc[pi][2]);
        acc[pi][3] = fmaf(zr[pi], wv.w, acc[pi][3]);
      }
    }
    float ub0 = upb[d4], ub1 = upb[d4+1], ub2 = upb[d4+2], ub3 = upb[d4+3];
    #pragma unroll
    for (int pi = 0; pi < 6; ++pi) {
      int l = (p0 - 1 + pi)*16 + jj;
      int col = l - l0 + 2;
      if (col >= 0 && col < 68) {
        bool v = ((unsigned)l < 1024u);
        up_s[(d4+0)*UPS + col] = v ? acc[pi][0] + ub0 : 0.f;
        up_s[(d4+1)*UPS + col] = v ? acc[pi][1] + ub1 : 0.f;
        up_s[(d4+2)*UPS + col] = v ? acc[pi][2] + ub2 : 0.f;
        up_s[(d4+3)*UPS + col] = v ? acc[pi][3] + ub3 : 0.f;
      }
    }
  }
  __syncthreads();

  {
    int o0 = w * 8;
    float accd[8];
    #pragma unroll
    for (int i = 0; i < 8; ++i) accd[i] = 0.f;
    for (int c = 0; c < 128; ++c) {
      float r0 = up_s[c*UPS + lane];
      float r1 = up_s[c*UPS + lane + 1];
      float r2 = up_s[c*UPS + lane + 2];
      const float* wb = w1dT + (size_t)c*192 + o0;   // (c*3+k)*64 + o0
      float4 wa0 = *(const float4*)(wb);
      float4 wa1 = *(const float4*)(wb + 4);
      float4 wb0 = *(const float4*)(wb + 64);
      float4 wb1 = *(const float4*)(wb + 68);
      float4 wc0 = *(const float4*)(wb + 128);
      float4 wc1 = *(const float4*)(wb + 132);
      accd[0] = fmaf(wa0.x, r0, fmaf(wb0.x, r1, fmaf(wc0.x, r2, accd[0])));
      accd[1] = fmaf(wa0.y, r0, fmaf(wb0.y, r1, fmaf(wc0.y, r2, accd[1])));
      accd[2] = fmaf(wa0.z, r0, fmaf(wb0.z, r1, fmaf(wc0.z, r2, accd[2])));
      accd[3] = fmaf(wa0.w, r0, fmaf(wb0.w, r1, fmaf(wc0.w, r2, accd[3])));
      accd[4] = fmaf(wa1.x, r0, fmaf(wb1.x, r1, fmaf(wc1.x, r2, accd[4])));
      accd[5] = fmaf(wa1.y, r0, fmaf(wb1.y, r1, fmaf(wc1.y, r2, accd[5])));
      accd[6] = fmaf(wa1.z, r0, fmaf(wb1.z, r1, fmaf(wc1.z, r2, accd[6])));
      accd[7] = fmaf(wa1.w, r0, fmaf(wb1.w, r1, fmaf(wc1.w, r2, accd[7])));
    }
    float hv = 0.f;
    int ho = t & 63, hc = 64 + (t >> 6);
    if (t < 128) {
      for (int c = 0; c < 128; ++c) {
        float q0 = up_s[c*UPS + hc];
        float q1 = up_s[c*UPS + hc + 1];
        float q2 = up_s[c*UPS + hc + 2];
        const float* wb = w1dT + (size_t)c*192 + ho;
        hv = fmaf(wb[0], q0, fmaf(wb[64], q1, fmaf(wb[128], q2, hv)));
      }
    }
    {
      int l = l0 - 1 + lane;
      bool v = ((unsigned)l < 1024u);
      #pragma unroll
      for (int i = 0; i < 8; ++i) {
        float x = accd[i] + db1[o0+i];
        dsh[(o0+i)*DS + lane] = v ? gelu_f(x) : 0.f;
      }
    }
    if (t < 128) {
      int l = l0 - 1 + hc;
      bool v = ((unsigned)l < 1024u);
      float x = hv + db1[ho];
      dsh[ho*DS + hc] = v ? gelu_f(x) : 0.f;
    }
  }
  if (t < 192) wd2[t] = dw2[t];
  __syncthreads();

  if (t < 256) {
    int loff = t & 63, ch = t >> 6;
    float part = 0.f;
    for (int cl = 0; cl < 16; ++cl) {
      int c = ch*16 + cl;
      part = fmaf(wd2[c*3+0], dsh[c*DS + loff],
             fmaf(wd2[c*3+1], dsh[c*DS + loff + 1],
             fmaf(wd2[c*3+2], dsh[c*DS + loff + 2], part)));
    }
    ztT[loff*4 + ch] = part;
  }
  __syncthreads();
  if (t < 64) {
    float acc = ztT[t*4+0] + ztT[t*4+1] + ztT[t*4+2] + ztT[t*4+3] + db2[0];
    float diff = acc - xn[(size_t)n*1024 + l0 + t];
    float part = diff*diff;
    for (int o = 32; o; o >>= 1) part += __shfl_down(part, o, 64);
    if (t == 0) recon_part[blk] = part;
  }
}

// ---------------- finalize loss ----------------
__global__ __launch_bounds__(256) void k_finalize(const float* __restrict__ ws, float* __restrict__ dout)
{
  const float* rp = ws + OFF_RP;
  const float* vp = ws + OFF_VP;
  int t = threadIdx.x;
  float s1 = 0.f, s2 = 0.f;
  for (int i = t; i < 8192; i += 256) s1 += rp[i];
  for (int i = t; i < 4096; i += 256) s2 += vp[i];
  __shared__ float sh[8];
  for (int o = 32; o; o >>= 1) { s1 += __shfl_down(s1,o,64); s2 += __shfl_down(s2,o,64); }
  if ((t & 63) == 0) { sh[t >> 6] = s1; sh[4 + (t >> 6)] = s2; }
  __syncthreads();
  if (t == 0) {
    float R = sh[0]+sh[1]+sh[2]+sh[3];
    float V = sh[4]+sh[5]+sh[6]+sh[7];
    dout[4194304] = R * (1.f/524288.f) + 0.25f * (V * (1.f/4194304.f));
  }
}

// ---------------- host ----------------
extern "C" void kernel_launch(void* const* d_in, const int* in_sizes, int n_in,
                              void* d_out, int out_size, void* d_ws, size_t ws_size,
                              hipStream_t stream)
{
  const float* x    = (const float*)d_in[0];
  const float* rw   = (const float*)d_in[1];
  const float* rb   = (const float*)d_in[2];
  const float* w1a  = (const float*)d_in[3];
  const float* b1a  = (const float*)d_in[4];
  const float* w2a  = (const float*)d_in[5];
  const float* b2a  = (const float*)d_in[6];
  const float* wda  = (const float*)d_in[7];
  const float* bda  = (const float*)d_in[8];
  const float* w1b  = (const float*)d_in[9];
  const float* b1b  = (const float*)d_in[10];
  const float* w2b  = (const float*)d_in[11];
  const float* b2b  = (const float*)d_in[12];
  const float* pw   = (const float*)d_in[13];
  const float* pb   = (const float*)d_in[14];
  const float* em   = (const float*)d_in[15];
  const float* upw  = (const float*)d_in[16];
  const float* upb  = (const float*)d_in[17];
  const float* dw1  = (const float*)d_in[18];
  const float* db1  = (const float*)d_in[19];
  const float* dw2  = (const float*)d_in[20];
  const float* db2  = (const float*)d_in[21];
  float* ws = (float*)d_ws;
  float* out = (float*)d_out;

  float* xn = ws + OFF_XN;
  float* pf = ws + OFF_PF;
  const float* w2aT = ws + OFF_W2A;
  const float* w1bT = ws + OFF_W1B;
  const float* w2bT = ws + OFF_W2B;
  const float* pwT  = ws + OFF_PW;

  k_prep<<<256, 256, 0, stream>>>(w2a, w1b, w2b, pw, upw, dw1, em, ws);
  k_revin<<<512, 256, 0, stream>>>(x, rw, rb, xn);
  k_enc<<<8192, 512, 0, stream>>>(xn, pf, w1a, b1a, w2aT, b2a, wda, bda,
                                  w1bT, b1b, w2bT, b2b, pwT, pb);
  k_vq<<<256, 256, 0, stream>>>(ws);
  k_gather<<<4096, 256, 0, stream>>>(ws, out);
  k_decoder<<<8192, 512, 0, stream>>>(out, ws, upb, db1, dw2, db2);
  k_finalize<<<1, 256, 0, stream>>>(ws, out);
}

// Round 10
// 3242.559 us; speedup vs baseline: 1.2594x; 1.2594x over previous
//
#include <hip/hip_runtime.h>

// ---------------- workspace layout (floats) ----------------
constexpr size_t OFF_XN  = 0;                      // 512*1024
constexpr size_t OFF_PF  = 524288;                 // 32768*128
constexpr size_t OFF_W2A = OFF_PF  + 4194304;      // [(cc*3+k)*128+d]
constexpr size_t OFF_W1B = OFF_W2A + 49152;
constexpr size_t OFF_W2B = OFF_W1B + 49152;
constexpr size_t OFF_PW  = OFF_W2B + 49152;        // [(c*16+k)*128+d]
constexpr size_t OFF_UPW = OFF_PW  + 262144;       // [(j*128+e)*128+d]
constexpr size_t OFF_W1D = OFF_UPW + 262144;       // [(c*3+k)*64+o]
constexpr size_t OFF_EMT = OFF_W1D + 24576;        // [j*128+d]
constexpr size_t OFF_EN  = OFF_EMT + 131072;       // 1024
constexpr size_t OFF_RP  = OFF_EN  + 1024;         // 8192
constexpr size_t OFF_VP  = OFF_RP  + 8192;         // 4096
constexpr size_t OFF_IND = OFF_VP  + 4096;         // 32768 int
// total ~21.7 MB

#define DI __device__ __forceinline__

// ---------------- prep: weight transposes + embedT + |e|^2 ----------------
__global__ __launch_bounds__(256) void k_prep(
    const float* __restrict__ w2a, const float* __restrict__ w1b, const float* __restrict__ w2b,
    const float* __restrict__ pw,  const float* __restrict__ upw, const float* __restrict__ w1d,
    const float* __restrict__ em,  float* __restrict__ ws)
{
  int tid = blockIdx.x * 256 + threadIdx.x;
  int stride = gridDim.x * 256;
  for (int i = tid; i < 128*128*3; i += stride) {
    int d = i / 384, r = i % 384;          // r = cc*3+k
    ws[OFF_W2A + (size_t)r*128 + d] = w2a[i];
    ws[OFF_W1B + (size_t)r*128 + d] = w1b[i];
    ws[OFF_W2B + (size_t)r*128 + d] = w2b[i];
  }
  for (int i = tid; i < 128*128*16; i += stride) {
    int d = i / 2048, r = i % 2048;        // r = c*16+k
    ws[OFF_PW + (size_t)r*128 + d] = pw[i];
  }
  for (int i = tid; i < 128*128*16; i += stride) {
    int e = i / 2048, rem = i % 2048;
    int d = rem / 16, j = rem % 16;
    ws[OFF_UPW + (size_t)(j*128 + e)*128 + d] = upw[i];
  }
  for (int i = tid; i < 64*128*3; i += stride) {
    int o = i / 384, r = i % 384;          // r = c*3+k
    ws[OFF_W1D + (size_t)r*64 + o] = w1d[i];
  }
  for (int j = tid; j < 1024; j += stride) {
    float s = 0.f;
    for (int d = 0; d < 128; ++d) {
      float v = em[d*1024 + j];
      ws[OFF_EMT + (size_t)j*128 + d] = v;
      s = fmaf(v, v, s);
    }
    ws[OFF_EN + j] = s;
  }
}

// ---------------- RevIN ----------------
__global__ __launch_bounds__(256) void k_revin(
    const float* __restrict__ x, const float* __restrict__ rw, const float* __restrict__ rb,
    float* __restrict__ xn)
{
  int n = blockIdx.x;            // sample = b*8 + c
  int b = n >> 3, c = n & 7;
  int t = threadIdx.x;
  const float* xp = x + (size_t)b*8192 + c;
  float v[4]; float s = 0.f, s2 = 0.f;
  #pragma unroll
  for (int i = 0; i < 4; ++i) {
    v[i] = xp[(size_t)(t + i*256)*8];
    s += v[i]; s2 = fmaf(v[i], v[i], s2);
  }
  __shared__ float sh[8];
  __shared__ float st[2];
  for (int o = 32; o; o >>= 1) { s += __shfl_down(s, o, 64); s2 += __shfl_down(s2, o, 64); }
  if ((t & 63) == 0) { sh[t >> 6] = s; sh[4 + (t >> 6)] = s2; }
  __syncthreads();
  if (t == 0) {
    float S = sh[0]+sh[1]+sh[2]+sh[3];
    float S2 = sh[4]+sh[5]+sh[6]+sh[7];
    float mu = S * (1.f/1024.f);
    float var = S2 * (1.f/1024.f) - mu*mu;
    st[0] = mu;
    st[1] = 1.f / sqrtf(var + 1e-5f);
  }
  __syncthreads();
  float mu = st[0], inv = st[1], w0 = rw[0], b0 = rb[0];
  #pragma unroll
  for (int i = 0; i < 4; ++i)
    xn[(size_t)n*1024 + t + i*256] = fmaf((v[i]-mu)*inv, w0, b0);
}

// ---------------- fully fused encoder ----------------
// block = (n, tile of 64 cols). 512 thr, 8 waves; wave w owns d-slice 16; lane = col.
// bufA [64][70]: h1a half (cc-split); later patchify partials [8cq][4p][128dd].
// bufB [128][68]: out0 (cols l0-4..l0+63) -> h1b (cols l0-2..l0+63) -> out1 (cols l0..l0+63).
// __launch_bounds__(512, 8): force VGPR <= 64 -- empirical 2-block/CU residency threshold
// (R7/R8 @64 VGPR -> 45% occ; R9 @68 VGPR -> 23% occ, 1 block/CU).
constexpr int STA = 70;
constexpr int STB = 68;

__global__ __launch_bounds__(512, 8) void k_enc(
    const float* __restrict__ xn, float* __restrict__ pf,
    const float* __restrict__ w1a, const float* __restrict__ b1a,
    const float* __restrict__ w2aT, const float* __restrict__ b2a,
    const float* __restrict__ wd,  const float* __restrict__ bd,
    const float* __restrict__ w1bT, const float* __restrict__ b1b,
    const float* __restrict__ w2bT, const float* __restrict__ b2b,
    const float* __restrict__ pwT, const float* __restrict__ pb)
{
  __shared__ float xs[72];
  __shared__ __align__(16) float bufA[64*STA];
  __shared__ __align__(16) float bufB[128*STB];
  int n = blockIdx.x >> 4, tile = blockIdx.x & 15;
  int l0 = tile * 64;
  int t = threadIdx.x;
  int lane = t & 63;
  int w = __builtin_amdgcn_readfirstlane(t >> 6);
  int d0 = w * 16;

  if (t < 72) {
    int gl = l0 - 8 + t;
    xs[t] = (gl >= 0) ? xn[(size_t)n*1024 + gl] : 0.f;
  }
  __syncthreads();

  float acc2[16];
  #pragma unroll
  for (int i = 0; i < 16; ++i) acc2[i] = 0.f;
  float hacc[4] = {0.f, 0.f, 0.f, 0.f};

  // ---- h1a (cc halves) + conv2 accumulation (verified R7 maps) ----
  for (int rep = 0; rep < 2; ++rep) {
    {                                   // h1a rows rep*64..+63, cols j<70 <-> l = l0-6+j
      int row = t & 63, colg = t >> 6;
      int c = rep*64 + row;
      float w0 = w1a[c*3+0], w1 = w1a[c*3+1], w2 = w1a[c*3+2], bb = b1a[c];
      #pragma unroll
      for (int i = 0; i < 9; ++i) {
        int j = colg*9 + i;
        if (j < 70) {
          float v = fmaf(w0, xs[j], fmaf(w1, xs[j+1], fmaf(w2, xs[j+2], bb)));
          bufA[row*STA + j] = (l0 - 6 + j >= 0) ? fmaxf(v, 0.f) : 0.f;
        }
      }
    }
    __syncthreads();
    for (int cc2 = 0; cc2 < 64; ++cc2) {   // conv2 main: out0 col l = l0+lane
      float r0 = bufA[cc2*STA + lane + 4];
      float r1 = bufA[cc2*STA + lane + 5];
      float r2 = bufA[cc2*STA + lane + 6];
      const float4* wp = (const float4*)(w2aT + (size_t)(rep*64 + cc2)*384 + d0);
      #pragma unroll
      for (int jj = 0; jj < 4; ++jj) {
        float4 a = wp[jj], b = wp[32+jj], c4 = wp[64+jj];
        acc2[jj*4+0] = fmaf(a.x, r0, fmaf(b.x, r1, fmaf(c4.x, r2, acc2[jj*4+0])));
        acc2[jj*4+1] = fmaf(a.y, r0, fmaf(b.y, r1, fmaf(c4.y, r2, acc2[jj*4+1])));
        acc2[jj*4+2] = fmaf(a.z, r0, fmaf(b.z, r1, fmaf(c4.z, r2, acc2[jj*4+2])));
        acc2[jj*4+3] = fmaf(a.w, r0, fmaf(b.w, r1, fmaf(c4.w, r2, acc2[jj*4+3])));
      }
    }
    if (t < 128) {                         // conv2 halo: out0 cols l0-4..l0-1, d = t
      for (int cc2 = 0; cc2 < 64; ++cc2) {
        const float* wp = w2aT + (size_t)(rep*64 + cc2)*384 + t;
        float w0 = wp[0], w1 = wp[128], w2 = wp[256];
        float q0 = bufA[cc2*STA+0], q1 = bufA[cc2*STA+1], q2 = bufA[cc2*STA+2],
              q3 = bufA[cc2*STA+3], q4 = bufA[cc2*STA+4], q5 = bufA[cc2*STA+5];
        hacc[0] = fmaf(w0, q0, fmaf(w1, q1, fmaf(w2, q2, hacc[0])));
        hacc[1] = fmaf(w0, q1, fmaf(w1, q2, fmaf(w2, q3, hacc[1])));
        hacc[2] = fmaf(w0, q2, fmaf(w1, q3, fmaf(w2, q4, hacc[2])));
        hacc[3] = fmaf(w0, q3, fmaf(w1, q4, fmaf(w2, q5, hacc[3])));
      }
    }
    __syncthreads();
  }

  // ---- out0 epilogue -> bufB (col j <-> l = l0-4+j); keep residual in regs ----
  float res[16];
  {
    float xv = xs[lane + 8];
    #pragma unroll
    for (int i = 0; i < 16; ++i) {
      int d = d0 + i;
      float o = fmaxf(fmaxf(acc2[i] + b2a[d], 0.f) + fmaf(wd[d], xv, bd[d]), 0.f);
      res[i] = o;                       // out0[d][l0+lane] kept for out1 residual
      bufB[d*STB + lane + 4] = o;
    }
    if (t < 128) {
      #pragma unroll
      for (int h = 0; h < 4; ++h) {
        int l = l0 - 4 + h;
        float o = 0.f;
        if (l >= 0)
          o = fmaxf(fmaxf(hacc[h] + b2a[t], 0.f) + fmaf(wd[t], xs[h+4], bd[t]), 0.f);
        bufB[t*STB + h] = o;
      }
    }
  }
  __syncthreads();

  // ---- conv3 single pass: h1b in regs (wave owns d-slice 16), then overwrite bufB ----
  {
    float acc3[16];
    #pragma unroll
    for (int i = 0; i < 16; ++i) acc3[i] = 0.f;
    // main: h1b[d0+i][gcol = l0-2+lane]; reads out0 window jb = lane..lane+2
    for (int cc = 0; cc < 128; ++cc) {
      float r0 = bufB[cc*STB + lane];
      float r1 = bufB[cc*STB + lane + 1];
      float r2 = bufB[cc*STB + lane + 2];
      const float4* wp = (const float4*)(w1bT + (size_t)cc*384 + d0);
      #pragma unroll
      for (int jj = 0; jj < 4; ++jj) {
        float4 a = wp[jj], b = wp[32+jj], c4 = wp[64+jj];
        acc3[jj*4+0] = fmaf(a.x, r0, fmaf(b.x, r1, fmaf(c4.x, r2, acc3[jj*4+0])));
        acc3[jj*4+1] = fmaf(a.y, r0, fmaf(b.y, r1, fmaf(c4.y, r2, acc3[jj*4+1])));
        acc3[jj*4+2] = fmaf(a.z, r0, fmaf(b.z, r1, fmaf(c4.z, r2, acc3[jj*4+2])));
        acc3[jj*4+3] = fmaf(a.w, r0, fmaf(b.w, r1, fmaf(c4.w, r2, acc3[jj*4+3])));
      }
    }
    // halo: h1b cols jh = 64,65 (gcol = l0+62, l0+63); out0 window jb = jh..jh+2
    float haccb = 0.f;
    int hrow = t & 127, hc = 64 + (t >> 7);   // t<256 active
    if (t < 256) {
      for (int cc = 0; cc < 128; ++cc) {
        float q0 = bufB[cc*STB + hc];
        float q1 = bufB[cc*STB + hc + 1];
        float q2 = bufB[cc*STB + hc + 2];
        const float* wp = w1bT + (size_t)cc*384 + hrow;
        haccb = fmaf(wp[0], q0, fmaf(wp[128], q1, fmaf(wp[256], q2, haccb)));
      }
    }
    __syncthreads();   // all out0 reads done; bufB reusable
    {
      bool valid = (l0 - 2 + lane >= 0);
      #pragma unroll
      for (int i = 0; i < 16; ++i)
        bufB[(d0+i)*STB + lane] = valid ? fmaxf(acc3[i] + b1b[d0+i], 0.f) : 0.f;
      if (t < 256)
        bufB[hrow*STB + hc] = fmaxf(haccb + b1b[hrow], 0.f);
    }
  }
  __syncthreads();

  // ---- conv4 single pass: out1 col l = l0+lane; h1b window = bufB[row][lane..lane+2] ----
  float acc4[16];
  #pragma unroll
  for (int i = 0; i < 16; ++i) acc4[i] = 0.f;
  for (int row = 0; row < 128; ++row) {
    float r0 = bufB[row*STB + lane];
    float r1 = bufB[row*STB + lane + 1];
    float r2 = bufB[row*STB + lane + 2];
    const float4* wp = (const float4*)(w2bT + (size_t)row*384 + d0);
    #pragma unroll
    for (int jj = 0; jj < 4; ++jj) {
      float4 a = wp[jj], b = wp[32+jj], c4 = wp[64+jj];
      acc4[jj*4+0] = fmaf(a.x, r0, fmaf(b.x, r1, fmaf(c4.x, r2, acc4[jj*4+0])));
      acc4[jj*4+1] = fmaf(a.y, r0, fmaf(b.y, r1, fmaf(c4.y, r2, acc4[jj*4+1])));
      acc4[jj*4+2] = fmaf(a.z, r0, fmaf(b.z, r1, fmaf(c4.z, r2, acc4[jj*4+2])));
      acc4[jj*4+3] = fmaf(a.w, r0, fmaf(b.w, r1, fmaf(c4.w, r2, acc4[jj*4+3])));
    }
  }
  __syncthreads();   // all h1b reads done
  // ---- out1 epilogue (residual from regs) -> bufB cols 0..63 ----
  #pragma unroll
  for (int i = 0; i < 16; ++i)
    bufB[(d0+i)*STB + lane] = fmaxf(fmaxf(acc4[i] + b2b[d0+i], 0.f) + res[i], 0.f);
  __syncthreads();

  // ---- patchify: thread (cq = t>>6, ddp = t&63) -> dd = 2ddp, 2ddp+1; c in [16cq,16cq+16) ----
  {
    int cq = t >> 6, ddp = t & 63;
    float acc[4][2] = {};
    for (int cl = 0; cl < 16; ++cl) {
      int c = cq*16 + cl;
      const float* row = bufB + c*STB;
      const float* wbase = pwT + (size_t)c*2048 + 2*ddp;
      #pragma unroll
      for (int k4 = 0; k4 < 4; ++k4) {
        float2 wv0 = *(const float2*)(wbase + (size_t)(k4*4+0)*128);
        float2 wv1 = *(const float2*)(wbase + (size_t)(k4*4+1)*128);
        float2 wv2 = *(const float2*)(wbase + (size_t)(k4*4+2)*128);
        float2 wv3 = *(const float2*)(wbase + (size_t)(k4*4+3)*128);
        #pragma unroll
        for (int p = 0; p < 4; ++p) {
          float4 av = *(const float4*)(row + p*16 + k4*4);
          acc[p][0] = fmaf(av.x, wv0.x, acc[p][0]);
          acc[p][1] = fmaf(av.x, wv0.y, acc[p][1]);
          acc[p][0] = fmaf(av.y, wv1.x, acc[p][0]);
          acc[p][1] = fmaf(av.y, wv1.y, acc[p][1]);
          acc[p][0] = fmaf(av.z, wv2.x, acc[p][0]);
          acc[p][1] = fmaf(av.z, wv2.y, acc[p][1]);
          acc[p][0] = fmaf(av.w, wv3.x, acc[p][0]);
          acc[p][1] = fmaf(av.w, wv3.y, acc[p][1]);
        }
      }
    }
    #pragma unroll
    for (int p = 0; p < 4; ++p)
      *(float2*)(bufA + (cq*4 + p)*128 + 2*ddp) = make_float2(acc[p][0], acc[p][1]);
  }
  __syncthreads();
  {
    int p = t >> 7, dd = t & 127;
    float s = 0.f;
    #pragma unroll
    for (int cq = 0; cq < 8; ++cq) s += bufA[(cq*4 + p)*128 + dd];
    pf[((size_t)n*64 + tile*4 + p)*128 + dd] = s + pb[dd];
  }
}

// ---------------- VQ argmin: dist' = |e|^2 - 2 f.e ----------------
__global__ __launch_bounds__(256) void k_vq(float* ws)
{
  __shared__ __align__(16) float fT[128*132];
  __shared__ __align__(16) float ech[64*128];
  __shared__ float ens[64];
  __shared__ float2 red[128*16];
  const float* pf  = ws + OFF_PF;
  const float* emT = ws + OFF_EMT;
  const float* en  = ws + OFF_EN;
  int* ind = (int*)(ws + OFF_IND);

  int t = threadIdx.x;
  int r0 = blockIdx.x * 128;
  for (int s = t; s < 16384; s += 256) {
    int rr = s >> 7, d = s & 127;
    fT[d*132 + rr] = pf[(size_t)(r0 + rr)*128 + d];
  }
  int rg = t & 15, jg = t >> 4;
  float bv[8]; int bi[8];
  #pragma unroll
  for (int r = 0; r < 8; ++r) { bv[r] = 3.4e38f; bi[r] = 0; }

  for (int ch = 0; ch < 16; ++ch) {
    __syncthreads();
    {
      const float4* src = (const float4*)(emT + (size_t)ch*8192);
      for (int q = t; q < 2048; q += 256) {
        int jj = q >> 5, dq4 = q & 31;
        *(float4*)(ech + jj*128 + ((dq4*4) ^ ((jj&7)<<2))) = src[q];
      }
      if (t < 64) ens[t] = en[ch*64 + t];
    }
    __syncthreads();
    float acc[8][4] = {};
    for (int db = 0; db < 128; db += 4) {
      float4 e0 = *(const float4*)(ech + (jg*4+0)*128 + (db ^ (((jg*4+0)&7)<<2)));
      float4 e1 = *(const float4*)(ech + (jg*4+1)*128 + (db ^ (((jg*4+1)&7)<<2)));
      float4 e2 = *(const float4*)(ech + (jg*4+2)*128 + (db ^ (((jg*4+2)&7)<<2)));
      float4 e3 = *(const float4*)(ech + (jg*4+3)*128 + (db ^ (((jg*4+3)&7)<<2)));
      #pragma unroll
      for (int u = 0; u < 4; ++u) {
        const float* fp = fT + (db+u)*132 + rg*8;
        float4 fa = *(const float4*)fp;
        float4 fb = *(const float4*)(fp + 4);
        float fv[8] = {fa.x,fa.y,fa.z,fa.w,fb.x,fb.y,fb.z,fb.w};
        float ev[4] = { ((const float*)&e0)[u], ((const float*)&e1)[u],
                        ((const float*)&e2)[u], ((const float*)&e3)[u] };
        #pragma unroll
        for (int r = 0; r < 8; ++r)
          #pragma unroll
          for (int j = 0; j < 4; ++j)
            acc[r][j] = fmaf(fv[r], ev[j], acc[r][j]);
      }
    }
    #pragma unroll
    for (int r = 0; r < 8; ++r)
      #pragma unroll
      for (int j = 0; j < 4; ++j) {
        float dist = ens[jg*4 + j] - 2.f*acc[r][j];
        int code = ch*64 + jg*4 + j;
        if (dist < bv[r]) { bv[r] = dist; bi[r] = code; }
      }
  }
  __syncthreads();
  #pragma unroll
  for (int r = 0; r < 8; ++r)
    red[(rg*8 + r)*16 + jg] = make_float2(bv[r], __int_as_float(bi[r]));
  __syncthreads();
  if (t < 128) {
    float2 v0 = red[t*16 + 0];
    float best = v0.x; int besti = __float_as_int(v0.y);
    for (int j = 1; j < 16; ++j) {
      float2 v = red[t*16 + j];
      int vi = __float_as_int(v.y);
      if (v.x < best || (v.x == best && vi < besti)) { best = v.x; besti = vi; }
    }
    ind[r0 + t] = besti;
  }
}

// ---------------- gather: z_q -> d_out, vq-loss partials ----------------
__global__ __launch_bounds__(256) void k_gather(float* ws, float* __restrict__ dout)
{
  const float* pf  = ws + OFF_PF;
  const float* emT = ws + OFF_EMT;
  const int* ind = (const int*)(ws + OFF_IND);
  float* vq_part = ws + OFF_VP;

  int t = threadIdx.x;
  int d = t & 127;
  float s = 0.f;
  #pragma unroll
  for (int it = 0; it < 4; ++it) {
    int rr = (t >> 7) + it*2;
    size_t row = (size_t)blockIdx.x*8 + rr;
    int idx = ind[row];
    float q = emT[(size_t)idx*128 + d];
    float f = pf[row*128 + d];
    float qm = q - f;
    dout[row*128 + d] = f + qm;
    s = fmaf(qm, qm, s);
  }
  __shared__ float sh[4];
  for (int o = 32; o; o >>= 1) s += __shfl_down(s, o, 64);
  if ((t & 63) == 0) sh[t >> 6] = s;
  __syncthreads();
  if (t == 0) vq_part[blockIdx.x] = sh[0]+sh[1]+sh[2]+sh[3];
}

DI float gelu_f(float x) {
  float u = x * fmaf(0.0356774081f, x*x, 0.7978845608f);
  float e = __expf(2.f * u);
  float th = 1.f - 2.f / (e + 1.f);
  return 0.5f * x * (1.f + th);
}

// ---------------- decoder: tile=64, 512 threads; D1 = encoder-style conv ----------------
__global__ __launch_bounds__(512) void k_decoder(
    const float* __restrict__ zq, float* ws,
    const float* __restrict__ upb, const float* __restrict__ db1,
    const float* __restrict__ dw2, const float* __restrict__ db2)
{
  constexpr int UPS = 70;   // up col j <-> l = l0-2+j, j=0..67 used
  constexpr int DS  = 70;   // d1 col j <-> l = l0-1+j, j=0..65 used
  __shared__ __align__(16) float ztT[128*8];
  __shared__ __align__(16) float up_s[128*UPS];
  __shared__ __align__(16) float dsh[64*DS];
  __shared__ __align__(16) float wd2[200];

  const float* upwT = ws + OFF_UPW;
  const float* w1dT = ws + OFF_W1D;
  const float* xn   = ws + OFF_XN;
  float* recon_part = ws + OFF_RP;

  int blk = blockIdx.x;
  int n = blk >> 4, tile = blk & 15;
  int l0 = tile*64, p0 = tile*4;
  int t = threadIdx.x;
  int lane = t & 63;
  int w = __builtin_amdgcn_readfirstlane(t >> 6);

  for (int s = t; s < 768; s += 512) {
    int e = s & 127, pi = s >> 7;
    int p = p0 - 1 + pi;
    ztT[e*8 + pi] = (p >= 0 && p < 64) ? zq[((size_t)n*64 + p)*128 + e] : 0.f;
  }
  __syncthreads();

  {
    int jj = t >> 5;
    int d4 = (t & 31) * 4;
    float acc[6][4] = {};
    const float* wbase = upwT + (size_t)jj*16384 + d4;
    for (int e = 0; e < 128; ++e) {
      float4 z0 = *(const float4*)(ztT + e*8);
      float2 z1 = *(const float2*)(ztT + e*8 + 4);
      float zr[6] = {z0.x, z0.y, z0.z, z0.w, z1.x, z1.y};
      float4 wv = *(const float4*)(wbase + (size_t)e*128);
      #pragma unroll
      for (int pi = 0; pi < 6; ++pi) {
        acc[pi][0] = fmaf(zr[pi], wv.x, acc[pi][0]);
        acc[pi][1] = fmaf(zr[pi], wv.y, acc[pi][1]);
        acc[pi][2] = fmaf(zr[pi], wv.z, acc[pi][2]);
        acc[pi][3] = fmaf(zr[pi], wv.w, acc[pi][3]);
      }
    }
    float ub0 = upb[d4], ub1 = upb[d4+1], ub2 = upb[d4+2], ub3 = upb[d4+3];
    #pragma unroll
    for (int pi = 0; pi < 6; ++pi) {
      int l = (p0 - 1 + pi)*16 + jj;
      int col = l - l0 + 2;
      if (col >= 0 && col < 68) {
        bool v = ((unsigned)l < 1024u);
        up_s[(d4+0)*UPS + col] = v ? acc[pi][0] + ub0 : 0.f;
        up_s[(d4+1)*UPS + col] = v ? acc[pi][1] + ub1 : 0.f;
        up_s[(d4+2)*UPS + col] = v ? acc[pi][2] + ub2 : 0.f;
        up_s[(d4+3)*UPS + col] = v ? acc[pi][3] + ub3 : 0.f;
      }
    }
  }
  __syncthreads();

  {
    int o0 = w * 8;
    float accd[8];
    #pragma unroll
    for (int i = 0; i < 8; ++i) accd[i] = 0.f;
    for (int c = 0; c < 128; ++c) {
      float r0 = up_s[c*UPS + lane];
      float r1 = up_s[c*UPS + lane + 1];
      float r2 = up_s[c*UPS + lane + 2];
      const float* wb = w1dT + (size_t)c*192 + o0;   // (c*3+k)*64 + o0
      float4 wa0 = *(const float4*)(wb);
      float4 wa1 = *(const float4*)(wb + 4);
      float4 wb0 = *(const float4*)(wb + 64);
      float4 wb1 = *(const float4*)(wb + 68);
      float4 wc0 = *(const float4*)(wb + 128);
      float4 wc1 = *(const float4*)(wb + 132);
      accd[0] = fmaf(wa0.x, r0, fmaf(wb0.x, r1, fmaf(wc0.x, r2, accd[0])));
      accd[1] = fmaf(wa0.y, r0, fmaf(wb0.y, r1, fmaf(wc0.y, r2, accd[1])));
      accd[2] = fmaf(wa0.z, r0, fmaf(wb0.z, r1, fmaf(wc0.z, r2, accd[2])));
      accd[3] = fmaf(wa0.w, r0, fmaf(wb0.w, r1, fmaf(wc0.w, r2, accd[3])));
      accd[4] = fmaf(wa1.x, r0, fmaf(wb1.x, r1, fmaf(wc1.x, r2, accd[4])));
      accd[5] = fmaf(wa1.y, r0, fmaf(wb1.y, r1, fmaf(wc1.y, r2, accd[5])));
      accd[6] = fmaf(wa1.z, r0, fmaf(wb1.z, r1, fmaf(wc1.z, r2, accd[6])));
      accd[7] = fmaf(wa1.w, r0, fmaf(wb1.w, r1, fmaf(wc1.w, r2, accd[7])));
    }
    float hv = 0.f;
    int ho = t & 63, hc = 64 + (t >> 6);
    if (t < 128) {
      for (int c = 0; c < 128; ++c) {
        float q0 = up_s[c*UPS + hc];
        float q1 = up_s[c*UPS + hc + 1];
        float q2 = up_s[c*UPS + hc + 2];
        const float* wb = w1dT + (size_t)c*192 + ho;
        hv = fmaf(wb[0], q0, fmaf(wb[64], q1, fmaf(wb[128], q2, hv)));
      }
    }
    {
      int l = l0 - 1 + lane;
      bool v = ((unsigned)l < 1024u);
      #pragma unroll
      for (int i = 0; i < 8; ++i) {
        float x = accd[i] + db1[o0+i];
        dsh[(o0+i)*DS + lane] = v ? gelu_f(x) : 0.f;
      }
    }
    if (t < 128) {
      int l = l0 - 1 + hc;
      bool v = ((unsigned)l < 1024u);
      float x = hv + db1[ho];
      dsh[ho*DS + hc] = v ? gelu_f(x) : 0.f;
    }
  }
  if (t < 192) wd2[t] = dw2[t];
  __syncthreads();

  if (t < 256) {
    int loff = t & 63, ch = t >> 6;
    float part = 0.f;
    for (int cl = 0; cl < 16; ++cl) {
      int c = ch*16 + cl;
      part = fmaf(wd2[c*3+0], dsh[c*DS + loff],
             fmaf(wd2[c*3+1], dsh[c*DS + loff + 1],
             fmaf(wd2[c*3+2], dsh[c*DS + loff + 2], part)));
    }
    ztT[loff*4 + ch] = part;
  }
  __syncthreads();
  if (t < 64) {
    float acc = ztT[t*4+0] + ztT[t*4+1] + ztT[t*4+2] + ztT[t*4+3] + db2[0];
    float diff = acc - xn[(size_t)n*1024 + l0 + t];
    float part = diff*diff;
    for (int o = 32; o; o >>= 1) part += __shfl_down(part, o, 64);
    if (t == 0) recon_part[blk] = part;
  }
}

// ---------------- finalize loss ----------------
__global__ __launch_bounds__(256) void k_finalize(const float* __restrict__ ws, float* __restrict__ dout)
{
  const float* rp = ws + OFF_RP;
  const float* vp = ws + OFF_VP;
  int t = threadIdx.x;
  float s1 = 0.f, s2 = 0.f;
  for (int i = t; i < 8192; i += 256) s1 += rp[i];
  for (int i = t; i < 4096; i += 256) s2 += vp[i];
  __shared__ float sh[8];
  for (int o = 32; o; o >>= 1) { s1 += __shfl_down(s1,o,64); s2 += __shfl_down(s2,o,64); }
  if ((t & 63) == 0) { sh[t >> 6] = s1; sh[4 + (t >> 6)] = s2; }
  __syncthreads();
  if (t == 0) {
    float R = sh[0]+sh[1]+sh[2]+sh[3];
    float V = sh[4]+sh[5]+sh[6]+sh[7];
    dout[4194304] = R * (1.f/524288.f) + 0.25f * (V * (1.f/4194304.f));
  }
}

// ---------------- host ----------------
extern "C" void kernel_launch(void* const* d_in, const int* in_sizes, int n_in,
                              void* d_out, int out_size, void* d_ws, size_t ws_size,
                              hipStream_t stream)
{
  const float* x    = (const float*)d_in[0];
  const float* rw   = (const float*)d_in[1];
  const float* rb   = (const float*)d_in[2];
  const float* w1a  = (const float*)d_in[3];
  const float* b1a  = (const float*)d_in[4];
  const float* w2a  = (const float*)d_in[5];
  const float* b2a  = (const float*)d_in[6];
  const float* wda  = (const float*)d_in[7];
  const float* bda  = (const float*)d_in[8];
  const float* w1b  = (const float*)d_in[9];
  const float* b1b  = (const float*)d_in[10];
  const float* w2b  = (const float*)d_in[11];
  const float* b2b  = (const float*)d_in[12];
  const float* pw   = (const float*)d_in[13];
  const float* pb   = (const float*)d_in[14];
  const float* em   = (const float*)d_in[15];
  const float* upw  = (const float*)d_in[16];
  const float* upb  = (const float*)d_in[17];
  const float* dw1  = (const float*)d_in[18];
  const float* db1  = (const float*)d_in[19];
  const float* dw2  = (const float*)d_in[20];
  const float* db2  = (const float*)d_in[21];
  float* ws = (float*)d_ws;
  float* out = (float*)d_out;

  float* xn = ws + OFF_XN;
  float* pf = ws + OFF_PF;
  const float* w2aT = ws + OFF_W2A;
  const float* w1bT = ws + OFF_W1B;
  const float* w2bT = ws + OFF_W2B;
  const float* pwT  = ws + OFF_PW;

  k_prep<<<256, 256, 0, stream>>>(w2a, w1b, w2b, pw, upw, dw1, em, ws);
  k_revin<<<512, 256, 0, stream>>>(x, rw, rb, xn);
  k_enc<<<8192, 512, 0, stream>>>(xn, pf, w1a, b1a, w2aT, b2a, wda, bda,
                                  w1bT, b1b, w2bT, b2b, pwT, pb);
  k_vq<<<256, 256, 0, stream>>>(ws);
  k_gather<<<4096, 256, 0, stream>>>(ws, out);
  k_decoder<<<8192, 512, 0, stream>>>(out, ws, upb, db1, dw2, db2);
  k_finalize<<<1, 256, 0, stream>>>(ws, out);
}